// Round 12
// baseline (2812.898 us; speedup 1.0000x reference)
//
#include <hip/hip_runtime.h>

typedef float f32x4 __attribute__((ext_vector_type(4)));
typedef __bf16 bf16x8 __attribute__((ext_vector_type(8)));
typedef unsigned short u16x8 __attribute__((ext_vector_type(8)));
typedef unsigned short u16x4 __attribute__((ext_vector_type(4)));

#define F 128

__device__ __forceinline__ unsigned short bf16_rne(float f) {
  unsigned u = __float_as_uint(f);
  u += 0x7FFFu + ((u >> 16) & 1u);
  return (unsigned short)(u >> 16);
}
__device__ __forceinline__ float bf16f(unsigned short s) {
  return __uint_as_float((unsigned)s << 16);
}

// Activation layout: ROW-MAJOR [node][128] u16 (hi and lo arrays).
// Weight layout FRAG-PACKED: per layer, frag ff = hs*24 + w*3 + part
// (hs = ks*2+g; g=0: Wc, g=1: Whh), storage [ff][hi 1KB][lo 1KB]; frag byte
// l*16+e*2 holds B[part*128 + w*16 + (l&15)][ks*32 + (l>>4)*8 + e].

// ---------------------------------------------------------------------------
// split8: x (f32, row-major) -> row-major bf16 hi/lo
// ---------------------------------------------------------------------------
__global__ void split8_kernel(const float* __restrict__ in,
                              unsigned short* __restrict__ hi, unsigned short* __restrict__ lo,
                              int N) {
  int i = blockIdx.x * 256 + threadIdx.x;  // over N*16
  if (i >= N * 16) return;
  int node = i >> 4, f8 = i & 15;
  const float4* p = (const float4*)(in + (size_t)node * F + f8 * 8);
  float4 a = p[0], b = p[1];
  float v[8] = {a.x, a.y, a.z, a.w, b.x, b.y, b.z, b.w};
  u16x8 vh, vl;
#pragma unroll
  for (int e = 0; e < 8; ++e) {
    unsigned short x = bf16_rne(v[e]);
    vh[e] = x;
    vl[e] = bf16_rne(v[e] - bf16f(x));
  }
  size_t o = (size_t)node * F + f8 * 8;
  *(u16x8*)(hi + o) = vh;
  *(u16x8*)(lo + o) = vl;
}

// ---------------------------------------------------------------------------
// prep_w: frag-packed combined weights.
//   Wc[t][j][k] = dot(W[t][k][:], w_ih[j][:]);  Whh[j][k] = w_hh[j][k]
// ---------------------------------------------------------------------------
__global__ void prep_w_kernel(const float* __restrict__ W, const float* __restrict__ w_ih,
                              const float* __restrict__ w_hh,
                              unsigned short* __restrict__ Bpack, int L) {
  int idx = blockIdx.x * 256 + threadIdx.x;
  if (idx >= L * 98304) return;
  int e = idx & 7;
  int l = (idx >> 3) & 63;
  int fp = idx >> 9;            // frag-value group: L*192
  int part = fp % 3;
  int rest = fp / 3;            // L*64
  int w = rest & 7, g = (rest >> 3) & 1, ks = (rest >> 4) & 3, t = rest >> 6;
  int j = part * 128 + w * 16 + (l & 15);
  int k = ks * 32 + ((l >> 4) & 3) * 8 + e;
  float v;
  if (g == 0) {
    const float* wi = w_ih + (size_t)j * 128;
    const float* wk = W + (size_t)t * 16384 + (size_t)k * 128;
    float acc = 0.f;
#pragma unroll 4
    for (int c = 0; c < 128; ++c) acc = fmaf(wk[c], wi[c], acc);
    v = acc;
  } else {
    v = w_hh[(size_t)j * 128 + k];
  }
  int ff = ((ks * 2 + g) * 8 + w) * 3 + part;
  size_t base = (size_t)t * 196608 + (size_t)ff * 1024 + l * 8 + e;
  unsigned short x = bf16_rne(v);
  Bpack[base] = x;
  Bpack[base + 512] = bf16_rne(v - bf16f(x));
}

// ---------------------------------------------------------------------------
// CSR build
// ---------------------------------------------------------------------------
__global__ void hist_kernel(const int* __restrict__ ei, int* __restrict__ cnt, int E) {
  int e = blockIdx.x * 256 + threadIdx.x;
  if (e < E) atomicAdd(&cnt[ei[E + e]], 1);
}

__global__ void scan1_kernel(const int* __restrict__ cnt, int* __restrict__ exscan,
                             int* __restrict__ chunk_sums, int N) {
  __shared__ int tmp[256];
  int i = blockIdx.x * 256 + threadIdx.x;
  int v = (i < N) ? cnt[i] : 0;
  tmp[threadIdx.x] = v;
  __syncthreads();
#pragma unroll
  for (int off = 1; off < 256; off <<= 1) {
    int a = (threadIdx.x >= off) ? tmp[threadIdx.x - off] : 0;
    __syncthreads();
    tmp[threadIdx.x] += a;
    __syncthreads();
  }
  if (i < N) exscan[i] = tmp[threadIdx.x] - v;
  if (threadIdx.x == 255) chunk_sums[blockIdx.x] = tmp[255];
}

__global__ void scan2_kernel(int* __restrict__ chunk_sums, int nchunk) {
  __shared__ int tmp[256];
  int v = (threadIdx.x < nchunk) ? chunk_sums[threadIdx.x] : 0;
  tmp[threadIdx.x] = v;
  __syncthreads();
#pragma unroll
  for (int off = 1; off < 256; off <<= 1) {
    int a = (threadIdx.x >= off) ? tmp[threadIdx.x - off] : 0;
    __syncthreads();
    tmp[threadIdx.x] += a;
    __syncthreads();
  }
  if (threadIdx.x < nchunk) chunk_sums[threadIdx.x] = tmp[threadIdx.x] - v;
}

__global__ void finalize_rowptr_kernel(const int* __restrict__ exscan,
                                       const int* __restrict__ chunk_sums,
                                       int* __restrict__ rowptr, int* __restrict__ cursor,
                                       int N, int E) {
  int i = blockIdx.x * 256 + threadIdx.x;
  if (i < N) {
    int v = exscan[i] + chunk_sums[i >> 8];
    rowptr[i] = v;
    cursor[i] = v;
  }
  if (i == N) rowptr[N] = E;
}

__global__ void place_kernel(const int* __restrict__ ei, int* __restrict__ cursor,
                             int* __restrict__ csr_src, int E) {
  int e = blockIdx.x * 256 + threadIdx.x;
  if (e >= E) return;
  int pos = atomicAdd(&cursor[ei[E + e]], 1);
  csr_src[pos] = ei[e];
}

// ---------------------------------------------------------------------------
// gather: one wave per node (unchanged from r9 — at HBM roofline).
// ---------------------------------------------------------------------------
__global__ __launch_bounds__(256) void gather_kernel(
    const unsigned short* __restrict__ hh, const unsigned short* __restrict__ hl,
    const int* __restrict__ rowptr, const int* __restrict__ csr_src,
    unsigned short* __restrict__ shi, unsigned short* __restrict__ slo, int N) {
  int node = blockIdx.x * 4 + (threadIdx.x >> 6);
  if (node >= N) return;
  const int lane = threadIdx.x & 63;
  const int grp = lane >> 4, sub = lane & 15;
  const int par = grp >> 1;
  const unsigned short* base = (grp & 1) ? hl : hh;
  const int beg = rowptr[node], end = rowptr[node + 1];
  float a[8] = {0.f, 0.f, 0.f, 0.f, 0.f, 0.f, 0.f, 0.f};
  int j = beg;
  for (; j + 8 <= end; j += 8) {
    int e0 = csr_src[j + par];
    int e1 = csr_src[j + 2 + par];
    int e2 = csr_src[j + 4 + par];
    int e3 = csr_src[j + 6 + par];
    u16x8 v0 = *(const u16x8*)(base + (size_t)e0 * F + sub * 8);
    u16x8 v1 = *(const u16x8*)(base + (size_t)e1 * F + sub * 8);
    u16x8 v2 = *(const u16x8*)(base + (size_t)e2 * F + sub * 8);
    u16x8 v3 = *(const u16x8*)(base + (size_t)e3 * F + sub * 8);
#pragma unroll
    for (int q = 0; q < 8; ++q)
      a[q] += (bf16f(v0[q]) + bf16f(v1[q])) + (bf16f(v2[q]) + bf16f(v3[q]));
  }
  for (; j + 2 <= end; j += 2) {
    int e0 = csr_src[j + par];
    u16x8 v0 = *(const u16x8*)(base + (size_t)e0 * F + sub * 8);
#pragma unroll
    for (int q = 0; q < 8; ++q) a[q] += bf16f(v0[q]);
  }
  if (j < end && par == 0) {
    int e0 = csr_src[j];
    u16x8 v0 = *(const u16x8*)(base + (size_t)e0 * F + sub * 8);
#pragma unroll
    for (int q = 0; q < 8; ++q) a[q] += bf16f(v0[q]);
  }
#pragma unroll
  for (int q = 0; q < 8; ++q) {
    a[q] += __shfl_xor(a[q], 32, 64);
    a[q] += __shfl_xor(a[q], 16, 64);
  }
  if (grp == 0) {
    u16x8 o;
#pragma unroll
    for (int q = 0; q < 8; ++q) o[q] = bf16_rne(a[q]);
    *(u16x8*)(shi + (size_t)node * F + sub * 8) = o;
  } else if (grp == 1) {
    u16x8 o;
#pragma unroll
    for (int q = 0; q < 8; ++q) {
      unsigned short x = bf16_rne(a[q]);
      o[q] = bf16_rne(a[q] - bf16f(x));
    }
    *(u16x8*)(slo + (size_t)node * F + sub * 8) = o;
  }
}

// ---------------------------------------------------------------------------
// gemm_gru (occupancy edition, FIXED): one 64-row chunk per block, 8 waves;
// wave w owns feature tile w. LDS = s ONLY (32KB, g2l-staged); the h@Whh
// A-fragments are loaded DIRECTLY from global (block's own rows, L2-hot).
// BUGFIX vs r11: per-lane h A-fragment address now includes the kq*16 byte
// K-sub-offset (ha[t] = r*256 + kq*16) — r11 dropped it, corrupting h@Whh.
// K-loop: 8 half-steps, 2-deep slots for B / As / Ah. Epilogue in 4x16-row
// sub-phases reusing the dead s region as the (a,b) float2 buffer.
// ---------------------------------------------------------------------------
__device__ __forceinline__ void g2l(const void* g, void* l) {
  __builtin_amdgcn_global_load_lds((const __attribute__((address_space(1))) void*)g,
                                   (__attribute__((address_space(3))) void*)l, 16, 0, 0);
}

#define LOADB(hs, slot)                                                          \
  {                                                                              \
    const unsigned char* bg = Bbase + (size_t)(hs) * 49152;                      \
    _Pragma("unroll") for (int i = 0; i < 6; ++i)                                \
        Bf[slot][i] = *(const bf16x8*)(bg + i * 1024);                           \
  }
#define LOADAS(ks, slot)                                                         \
  {                                                                              \
    const unsigned char* p0 = lds + (ks) * 4096 + lrow * 64 + kq * 16;           \
    _Pragma("unroll") for (int t = 0; t < 4; ++t) {                              \
      As[slot][t] = *(const bf16x8*)(p0 + t * 1024);                             \
      As[slot][4 + t] = *(const bf16x8*)(p0 + 16384 + t * 1024);                 \
    }                                                                            \
  }
#define LOADH(ks, slot)                                                          \
  {                                                                              \
    _Pragma("unroll") for (int t = 0; t < 4; ++t) {                              \
      Ah[slot][t] = *(const bf16x8*)((const unsigned char*)h_hi + ha[t] + (ks) * 64);     \
      Ah[slot][4 + t] = *(const bf16x8*)((const unsigned char*)h_lo + ha[t] + (ks) * 64); \
    }                                                                            \
  }
#define DOMFMA(hs, bslot, ARR, aslot)                                            \
  {                                                                              \
    const int g_ = (hs) & 1;                                                     \
    __builtin_amdgcn_s_setprio(1);                                               \
    _Pragma("unroll") for (int part = 0; part < 3; ++part)                       \
        _Pragma("unroll") for (int t = 0; t < 4; ++t) {                          \
      const int ai = (part == 2) ? (t * 4 + 2 + g_) : (t * 4 + part);            \
      acc[ai] = __builtin_amdgcn_mfma_f32_16x16x32_bf16(ARR[aslot][t], Bf[bslot][part * 2], acc[ai], 0, 0, 0);     \
      acc[ai] = __builtin_amdgcn_mfma_f32_16x16x32_bf16(ARR[aslot][4 + t], Bf[bslot][part * 2], acc[ai], 0, 0, 0); \
      acc[ai] = __builtin_amdgcn_mfma_f32_16x16x32_bf16(ARR[aslot][t], Bf[bslot][part * 2 + 1], acc[ai], 0, 0, 0); \
    }                                                                            \
    __builtin_amdgcn_s_setprio(0);                                               \
  }

#define ABSTRIDE 1056

__global__ __launch_bounds__(512, 6) void gemm_gru_kernel(
    const unsigned short* __restrict__ s_hi, const unsigned short* __restrict__ s_lo,
    const unsigned short* h_hi, const unsigned short* h_lo,
    const unsigned short* __restrict__ Bpack,
    const float* __restrict__ bih, const float* __restrict__ bhh,
    unsigned short* h_hi_out, unsigned short* h_lo_out, int N) {
  __shared__ __align__(1024) unsigned char lds[32768];  // s only; ab reuses it
  const int tid = threadIdx.x, w = tid >> 6, lane = tid & 63;
  const int lrow = lane & 15, kq = lane >> 4;
  const int row0 = blockIdx.x * 64;

  // ---- stage s: 32 x 1KB chunks; wave w -> arr = w>>2, ks = w&3, quarters 0..3
  {
    const unsigned short* ap = (w >= 4) ? s_lo : s_hi;
    const int wk_ = w & 3;
#pragma unroll
    for (int i = 0; i < 4; ++i) {
      int r = row0 + i * 16 + (lane >> 2);
      if (r >= N) r = N - 1;
      const unsigned short* g = ap + (size_t)r * F + wk_ * 32 + (lane & 3) * 8;
      g2l(g, lds + (((w >> 2) * 16 + wk_ * 4 + i) * 1024) + lane * 16);
    }
  }

  // per-lane clamped byte offsets of this block's h rows (A-fragment rows),
  // INCLUDING the per-lane K-sub-offset kq*16 bytes (r11 bugfix)
  unsigned ha[4];
#pragma unroll
  for (int t = 0; t < 4; ++t) {
    int r = row0 + t * 16 + lrow;
    if (r >= N) r = N - 1;
    ha[t] = (unsigned)r * 256u + (unsigned)kq * 16u;
  }

  f32x4 acc[16];  // [t*4 + q], q: 0=r(merged), 1=z(merged), 2=n_c1, 3=n_c2
#pragma unroll
  for (int i = 0; i < 16; ++i) acc[i] = (f32x4){0.f, 0.f, 0.f, 0.f};
  bf16x8 Bf[2][6];
  bf16x8 As[2][8];
  bf16x8 Ah[2][8];

  const unsigned char* Bbase = (const unsigned char*)Bpack + (size_t)w * 6144 + lane * 16;

  asm volatile("s_waitcnt vmcnt(0)" ::: "memory");
  __syncthreads();

  // ---- K-loop: 8 half-steps, loads issued ~1 DOMFMA ahead
  LOADB(0, 0) LOADAS(0, 0) LOADH(0, 0) LOADB(1, 1)
  DOMFMA(0, 0, As, 0) LOADB(2, 0) LOADAS(1, 1)
  DOMFMA(1, 1, Ah, 0) LOADB(3, 1) LOADH(1, 1)
  DOMFMA(2, 0, As, 1) LOADB(4, 0) LOADAS(2, 0)
  DOMFMA(3, 1, Ah, 1) LOADB(5, 1) LOADH(2, 0)
  DOMFMA(4, 0, As, 0) LOADB(6, 0) LOADAS(3, 1)
  DOMFMA(5, 1, Ah, 0) LOADB(7, 1) LOADH(3, 1)
  DOMFMA(6, 0, As, 1)
  DOMFMA(7, 1, Ah, 1)

  __syncthreads();  // K-loop done; s region becomes ab-space

  // ---- epilogue: 4 sub-phases of 16 rows (acc tile t)
  const int c = w * 16 + lrow;
  const float br = bih[c] + bhh[c];
  const float bz = bih[128 + c] + bhh[128 + c];
  const float bni = bih[256 + c], bnh = bhh[256 + c];
  const int prow = tid >> 5;        // phase-2: row within 16-row tile
  const int pcol = (tid & 31) * 4;  // phase-2: 4 features

#pragma unroll
  for (int t = 0; t < 4; ++t) {
    // phase-1: gates for rows [row0 + t*16, +16) -> (a,b) float2 in ab-LDS
    {
      unsigned char* abp = lds + (size_t)(kq * 4) * ABSTRIDE + c * 8;
#pragma unroll
      for (int i = 0; i < 4; ++i) {
        const float cr = acc[t * 4 + 0][i];
        const float cz = acc[t * 4 + 1][i];
        const float c1n = acc[t * 4 + 2][i], c2n = acc[t * 4 + 3][i];
        const float rr = 1.f / (1.f + __expf(-(cr + br)));
        const float zz = 1.f / (1.f + __expf(-(cz + bz)));
        const float nn = tanhf(c1n + bni + rr * (c2n + bnh));
        *(float2*)(abp + (size_t)i * ABSTRIDE) = make_float2((1.f - zz) * nn, zz);
      }
    }
    __syncthreads();
    // phase-2: wide h RMW for these 16 rows
    {
      const int r = row0 + t * 16 + prow;
      if (r < N) {
        const float2* ab = (const float2*)(lds + (size_t)prow * ABSTRIDE + pcol * 8);
        const size_t go = (size_t)r * F + pcol;
        u16x4 vh = *(const u16x4*)(h_hi_out + go);
        u16x4 vl = *(const u16x4*)(h_lo_out + go);
        u16x4 oh, ol;
#pragma unroll
        for (int k2 = 0; k2 < 4; ++k2) {
          float hold = bf16f(vh[k2]) + bf16f(vl[k2]);
          float2 pq = ab[k2];
          float hn = pq.x + pq.y * hold;
          unsigned short x = bf16_rne(hn);
          oh[k2] = x;
          ol[k2] = bf16_rne(hn - bf16f(x));
        }
        *(u16x4*)(h_hi_out + go) = oh;
        *(u16x4*)(h_lo_out + go) = ol;
      }
    }
    if (t < 3) __syncthreads();  // protect ab before next phase-1 overwrite
  }
}

// ---------------------------------------------------------------------------
// final: out[n] = relu(h[n]) . lin_w + lin_b
// ---------------------------------------------------------------------------
__global__ void final_kernel(const unsigned* __restrict__ hh, const unsigned* __restrict__ hl,
                             const float* __restrict__ lin_w,
                             const float* __restrict__ lin_b, float* __restrict__ out, int N) {
  int n = blockIdx.x * 4 + (threadIdx.x >> 6);
  if (n >= N) return;
  int d = threadIdx.x & 63;
  size_t o = (size_t)n * 64 + d;  // u32 view of row-major [node][128] u16
  unsigned wh = hh[o], wl = hl[o];
  float v0 = bf16f((unsigned short)(wh & 0xffff)) + bf16f((unsigned short)(wl & 0xffff));
  float v1 = bf16f((unsigned short)(wh >> 16)) + bf16f((unsigned short)(wl >> 16));
  float sum = fmaxf(v0, 0.f) * lin_w[2 * d] + fmaxf(v1, 0.f) * lin_w[2 * d + 1];
#pragma unroll
  for (int s = 32; s; s >>= 1) sum += __shfl_xor(sum, s, 64);
  if (d == 0) out[n] = sum + lin_b[0];
}

// ---------------------------------------------------------------------------
extern "C" void kernel_launch(void* const* d_in, const int* in_sizes, int n_in,
                              void* d_out, int out_size, void* d_ws, size_t ws_size,
                              hipStream_t stream) {
  const float* x     = (const float*)d_in[0];
  const int*   ei    = (const int*)d_in[1];
  const float* W     = (const float*)d_in[2];
  const float* w_ih  = (const float*)d_in[3];
  const float* w_hh  = (const float*)d_in[4];
  const float* b_ih  = (const float*)d_in[5];
  const float* b_hh  = (const float*)d_in[6];
  const float* lin_w = (const float*)d_in[7];
  const float* lin_b = (const float*)d_in[8];

  const int N = in_sizes[0] / F;
  const int E = in_sizes[1] / 2;
  const int L = in_sizes[2] / (F * F);
  const size_t NF = (size_t)N * F;

  char* p = (char*)d_ws;
  unsigned short* h_hi = (unsigned short*)p; p += NF * 2;
  unsigned short* h_lo = (unsigned short*)p; p += NF * 2;
  unsigned short* s_hi = (unsigned short*)p; p += NF * 2;
  unsigned short* s_lo = (unsigned short*)p; p += NF * 2;
  unsigned short* Bpack = (unsigned short*)p; p += (size_t)L * 196608 * 2;
  int* cnt     = (int*)p; p += (size_t)N * 4;
  int* exscan  = (int*)p; p += (size_t)N * 4;
  int* chunk   = (int*)p; p += 256 * 4;
  int* rowptr  = (int*)p; p += ((size_t)N + 1) * 4;
  int* cursor  = (int*)p; p += (size_t)N * 4;
  int* csr_src = (int*)p; p += (size_t)E * 4;

  const int split_blocks = (N * 16 + 255) / 256;
  const int prep_blocks = (L * 98304 + 255) / 256;
  const int edge_blocks = (E + 255) / 256;
  const int nchunk = (N + 255) / 256;
  const int gemm_blocks = (N + 63) / 64;
  const int node4_blocks = (N + 3) / 4;

  split8_kernel<<<split_blocks, 256, 0, stream>>>(x, h_hi, h_lo, N);
  prep_w_kernel<<<prep_blocks, 256, 0, stream>>>(W, w_ih, w_hh, Bpack, L);

  hipMemsetAsync(cnt, 0, (size_t)N * 4, stream);
  hist_kernel<<<edge_blocks, 256, 0, stream>>>(ei, cnt, E);
  scan1_kernel<<<nchunk, 256, 0, stream>>>(cnt, exscan, chunk, N);
  scan2_kernel<<<1, 256, 0, stream>>>(chunk, nchunk);
  finalize_rowptr_kernel<<<(N + 256) / 256, 256, 0, stream>>>(exscan, chunk, rowptr, cursor, N, E);
  place_kernel<<<edge_blocks, 256, 0, stream>>>(ei, cursor, csr_src, E);

  for (int t = 0; t < L; ++t) {
    gather_kernel<<<node4_blocks, 256, 0, stream>>>(
        h_hi, h_lo, rowptr, csr_src, s_hi, s_lo, N);
    gemm_gru_kernel<<<gemm_blocks, 512, 0, stream>>>(
        s_hi, s_lo, h_hi, h_lo, Bpack + (size_t)t * 196608,
        b_ih, b_hh, h_hi, h_lo, N);
  }

  final_kernel<<<node4_blocks, 256, 0, stream>>>(
      (const unsigned*)h_hi, (const unsigned*)h_lo, lin_w, lin_b, (float*)d_out, N);
}

// Round 13
// 724.640 us; speedup vs baseline: 3.8818x; 3.8818x over previous
//
#include <hip/hip_runtime.h>

typedef float f32x4 __attribute__((ext_vector_type(4)));
typedef __bf16 bf16x8 __attribute__((ext_vector_type(8)));
typedef unsigned short u16x8 __attribute__((ext_vector_type(8)));
typedef unsigned short u16x4 __attribute__((ext_vector_type(4)));

#define F 128

__device__ __forceinline__ unsigned short bf16_rne(float f) {
  unsigned u = __float_as_uint(f);
  u += 0x7FFFu + ((u >> 16) & 1u);
  return (unsigned short)(u >> 16);
}
__device__ __forceinline__ float bf16f(unsigned short s) {
  return __uint_as_float((unsigned)s << 16);
}

// Activation layout: ROW-MAJOR [node][128] u16 (hi and lo arrays).
// Weight layout FRAG-PACKED: per layer, frag ff = hs*24 + w*3 + part
// (hs = ks*2+g; g=0: Wc, g=1: Whh), storage [ff][hi 1KB][lo 1KB]; frag byte
// l*16+e*2 holds B[part*128 + w*16 + (l&15)][ks*32 + (l>>4)*8 + e].

// ---------------------------------------------------------------------------
// split8: x (f32, row-major) -> row-major bf16 hi/lo
// ---------------------------------------------------------------------------
__global__ void split8_kernel(const float* __restrict__ in,
                              unsigned short* __restrict__ hi, unsigned short* __restrict__ lo,
                              int N) {
  int i = blockIdx.x * 256 + threadIdx.x;  // over N*16
  if (i >= N * 16) return;
  int node = i >> 4, f8 = i & 15;
  const float4* p = (const float4*)(in + (size_t)node * F + f8 * 8);
  float4 a = p[0], b = p[1];
  float v[8] = {a.x, a.y, a.z, a.w, b.x, b.y, b.z, b.w};
  u16x8 vh, vl;
#pragma unroll
  for (int e = 0; e < 8; ++e) {
    unsigned short x = bf16_rne(v[e]);
    vh[e] = x;
    vl[e] = bf16_rne(v[e] - bf16f(x));
  }
  size_t o = (size_t)node * F + f8 * 8;
  *(u16x8*)(hi + o) = vh;
  *(u16x8*)(lo + o) = vl;
}

// ---------------------------------------------------------------------------
// prep_w: frag-packed combined weights.
//   Wc[t][j][k] = dot(W[t][k][:], w_ih[j][:]);  Whh[j][k] = w_hh[j][k]
// ---------------------------------------------------------------------------
__global__ void prep_w_kernel(const float* __restrict__ W, const float* __restrict__ w_ih,
                              const float* __restrict__ w_hh,
                              unsigned short* __restrict__ Bpack, int L) {
  int idx = blockIdx.x * 256 + threadIdx.x;
  if (idx >= L * 98304) return;
  int e = idx & 7;
  int l = (idx >> 3) & 63;
  int fp = idx >> 9;            // frag-value group: L*192
  int part = fp % 3;
  int rest = fp / 3;            // L*64
  int w = rest & 7, g = (rest >> 3) & 1, ks = (rest >> 4) & 3, t = rest >> 6;
  int j = part * 128 + w * 16 + (l & 15);
  int k = ks * 32 + ((l >> 4) & 3) * 8 + e;
  float v;
  if (g == 0) {
    const float* wi = w_ih + (size_t)j * 128;
    const float* wk = W + (size_t)t * 16384 + (size_t)k * 128;
    float acc = 0.f;
#pragma unroll 4
    for (int c = 0; c < 128; ++c) acc = fmaf(wk[c], wi[c], acc);
    v = acc;
  } else {
    v = w_hh[(size_t)j * 128 + k];
  }
  int ff = ((ks * 2 + g) * 8 + w) * 3 + part;
  size_t base = (size_t)t * 196608 + (size_t)ff * 1024 + l * 8 + e;
  unsigned short x = bf16_rne(v);
  Bpack[base] = x;
  Bpack[base + 512] = bf16_rne(v - bf16f(x));
}

// ---------------------------------------------------------------------------
// CSR build
// ---------------------------------------------------------------------------
__global__ void hist_kernel(const int* __restrict__ ei, int* __restrict__ cnt, int E) {
  int e = blockIdx.x * 256 + threadIdx.x;
  if (e < E) atomicAdd(&cnt[ei[E + e]], 1);
}

__global__ void scan1_kernel(const int* __restrict__ cnt, int* __restrict__ exscan,
                             int* __restrict__ chunk_sums, int N) {
  __shared__ int tmp[256];
  int i = blockIdx.x * 256 + threadIdx.x;
  int v = (i < N) ? cnt[i] : 0;
  tmp[threadIdx.x] = v;
  __syncthreads();
#pragma unroll
  for (int off = 1; off < 256; off <<= 1) {
    int a = (threadIdx.x >= off) ? tmp[threadIdx.x - off] : 0;
    __syncthreads();
    tmp[threadIdx.x] += a;
    __syncthreads();
  }
  if (i < N) exscan[i] = tmp[threadIdx.x] - v;
  if (threadIdx.x == 255) chunk_sums[blockIdx.x] = tmp[255];
}

__global__ void scan2_kernel(int* __restrict__ chunk_sums, int nchunk) {
  __shared__ int tmp[256];
  int v = (threadIdx.x < nchunk) ? chunk_sums[threadIdx.x] : 0;
  tmp[threadIdx.x] = v;
  __syncthreads();
#pragma unroll
  for (int off = 1; off < 256; off <<= 1) {
    int a = (threadIdx.x >= off) ? tmp[threadIdx.x - off] : 0;
    __syncthreads();
    tmp[threadIdx.x] += a;
    __syncthreads();
  }
  if (threadIdx.x < nchunk) chunk_sums[threadIdx.x] = tmp[threadIdx.x] - v;
}

__global__ void finalize_rowptr_kernel(const int* __restrict__ exscan,
                                       const int* __restrict__ chunk_sums,
                                       int* __restrict__ rowptr, int* __restrict__ cursor,
                                       int N, int E) {
  int i = blockIdx.x * 256 + threadIdx.x;
  if (i < N) {
    int v = exscan[i] + chunk_sums[i >> 8];
    rowptr[i] = v;
    cursor[i] = v;
  }
  if (i == N) rowptr[N] = E;
}

__global__ void place_kernel(const int* __restrict__ ei, int* __restrict__ cursor,
                             int* __restrict__ csr_src, int E) {
  int e = blockIdx.x * 256 + threadIdx.x;
  if (e >= E) return;
  int pos = atomicAdd(&cursor[ei[E + e]], 1);
  csr_src[pos] = ei[e];
}

// ---------------------------------------------------------------------------
// gather: one wave per node (r8-proven, near fabric roofline).
// ---------------------------------------------------------------------------
__global__ __launch_bounds__(256) void gather_kernel(
    const unsigned short* __restrict__ hh, const unsigned short* __restrict__ hl,
    const int* __restrict__ rowptr, const int* __restrict__ csr_src,
    unsigned short* __restrict__ shi, unsigned short* __restrict__ slo, int N) {
  int node = blockIdx.x * 4 + (threadIdx.x >> 6);
  if (node >= N) return;
  const int lane = threadIdx.x & 63;
  const int grp = lane >> 4, sub = lane & 15;
  const int par = grp >> 1;
  const unsigned short* base = (grp & 1) ? hl : hh;
  const int beg = rowptr[node], end = rowptr[node + 1];
  float a[8] = {0.f, 0.f, 0.f, 0.f, 0.f, 0.f, 0.f, 0.f};
  int j = beg;
  for (; j + 8 <= end; j += 8) {
    int e0 = csr_src[j + par];
    int e1 = csr_src[j + 2 + par];
    int e2 = csr_src[j + 4 + par];
    int e3 = csr_src[j + 6 + par];
    u16x8 v0 = *(const u16x8*)(base + (size_t)e0 * F + sub * 8);
    u16x8 v1 = *(const u16x8*)(base + (size_t)e1 * F + sub * 8);
    u16x8 v2 = *(const u16x8*)(base + (size_t)e2 * F + sub * 8);
    u16x8 v3 = *(const u16x8*)(base + (size_t)e3 * F + sub * 8);
#pragma unroll
    for (int q = 0; q < 8; ++q)
      a[q] += (bf16f(v0[q]) + bf16f(v1[q])) + (bf16f(v2[q]) + bf16f(v3[q]));
  }
  for (; j + 2 <= end; j += 2) {
    int e0 = csr_src[j + par];
    u16x8 v0 = *(const u16x8*)(base + (size_t)e0 * F + sub * 8);
#pragma unroll
    for (int q = 0; q < 8; ++q) a[q] += bf16f(v0[q]);
  }
  if (j < end && par == 0) {
    int e0 = csr_src[j];
    u16x8 v0 = *(const u16x8*)(base + (size_t)e0 * F + sub * 8);
#pragma unroll
    for (int q = 0; q < 8; ++q) a[q] += bf16f(v0[q]);
  }
#pragma unroll
  for (int q = 0; q < 8; ++q) {
    a[q] += __shfl_xor(a[q], 32, 64);
    a[q] += __shfl_xor(a[q], 16, 64);
  }
  if (grp == 0) {
    u16x8 o;
#pragma unroll
    for (int q = 0; q < 8; ++q) o[q] = bf16_rne(a[q]);
    *(u16x8*)(shi + (size_t)node * F + sub * 8) = o;
  } else if (grp == 1) {
    u16x8 o;
#pragma unroll
    for (int q = 0; q < 8; ++q) {
      unsigned short x = bf16_rne(a[q]);
      o[q] = bf16_rne(a[q] - bf16f(x));
    }
    *(u16x8*)(slo + (size_t)node * F + sub * 8) = o;
  }
}

// ---------------------------------------------------------------------------
// gemm_gru (PERSISTENT): grid = min(256, nchunks) blocks, 1/CU (82.4KB LDS);
// each block loops over chunks bid, bid+grid, ... Per chunk: A (s,h hi/lo)
// in LDS[0..64K); K-loop = r8's 2-deep pipeline with r9's merged acc[16];
// after the post-K barrier the NEXT chunk's A-stage is issued (g2l into the
// now-dead A region) so its latency hides under the epilogue. Epilogue uses
// a SEPARATE 16.9KB ab-buffer (LDS[64K..]) in 4x16-row sub-phases (r12-
// proven); h RMW loads for all 4 sub-phases issued early. tanh via guarded
// exp-form. launch_bounds(512,2) — never demand >2 waves/SIMD (r12 lesson).
// ---------------------------------------------------------------------------
__device__ __forceinline__ void g2l(const void* g, void* l) {
  __builtin_amdgcn_global_load_lds((const __attribute__((address_space(1))) void*)g,
                                   (__attribute__((address_space(3))) void*)l, 16, 0, 0);
}

#define LOADB(hs, slot)                                                          \
  {                                                                              \
    const unsigned char* bg = Bbase + (size_t)(hs) * 49152;                      \
    _Pragma("unroll") for (int i = 0; i < 6; ++i)                                \
        Bf[slot][i] = *(const bf16x8*)(bg + i * 1024);                           \
  }
#define LOADA(hs, slot)                                                          \
  {                                                                              \
    const int ks_ = (hs) >> 1, g_ = (hs) & 1;                                    \
    const unsigned char* bh = lds + ((g_ * 2) * 4 + ks_) * 4096 + lrow * 64 + kq * 16;      \
    const unsigned char* bl = lds + ((g_ * 2 + 1) * 4 + ks_) * 4096 + lrow * 64 + kq * 16;  \
    _Pragma("unroll") for (int t = 0; t < 4; ++t) {                              \
      Af[slot][t] = *(const bf16x8*)(bh + t * 1024);                             \
      Af[slot][4 + t] = *(const bf16x8*)(bl + t * 1024);                         \
    }                                                                            \
  }
#define DOMFMA(hs, slot)                                                         \
  {                                                                              \
    const int g_ = (hs) & 1;                                                     \
    __builtin_amdgcn_s_setprio(1);                                               \
    _Pragma("unroll") for (int part = 0; part < 3; ++part)                       \
        _Pragma("unroll") for (int t = 0; t < 4; ++t) {                          \
      const int ai = (part == 2) ? (t * 4 + 2 + g_) : (t * 4 + part);            \
      acc[ai] = __builtin_amdgcn_mfma_f32_16x16x32_bf16(Af[slot][t], Bf[slot][part * 2], acc[ai], 0, 0, 0);     \
      acc[ai] = __builtin_amdgcn_mfma_f32_16x16x32_bf16(Af[slot][4 + t], Bf[slot][part * 2], acc[ai], 0, 0, 0); \
      acc[ai] = __builtin_amdgcn_mfma_f32_16x16x32_bf16(Af[slot][t], Bf[slot][part * 2 + 1], acc[ai], 0, 0, 0); \
    }                                                                            \
    __builtin_amdgcn_s_setprio(0);                                               \
  }

#define ABSTRIDE 1056
#define ABBASE 65536

__global__ __launch_bounds__(512, 2) void gemm_gru_kernel(
    const unsigned short* __restrict__ s_hi, const unsigned short* __restrict__ s_lo,
    const unsigned short* h_hi, const unsigned short* h_lo,
    const unsigned short* __restrict__ Bpack,
    const float* __restrict__ bih, const float* __restrict__ bhh,
    unsigned short* h_hi_out, unsigned short* h_lo_out, int N, int nchunks) {
  __shared__ __align__(1024) unsigned char lds[ABBASE + 16 * ABSTRIDE];  // 82432B
  const int tid = threadIdx.x, w = tid >> 6, lane = tid & 63;
  const int lrow = lane & 15, kq = lane >> 4;

  auto stageA = [&](int row0s) {
    const int arr = w >> 1;  // wave-constant: s_hi, s_lo, h_hi, h_lo
    const unsigned short* ap = (arr == 0) ? s_hi : (arr == 1) ? s_lo : (arr == 2) ? h_hi : h_lo;
#pragma unroll
    for (int i = 0; i < 8; ++i) {
      const int ks = (2 * w + (i >> 2)) & 3;
      int r = row0s + (i & 3) * 16 + (lane >> 2);
      if (r >= N) r = N - 1;
      const unsigned short* g = ap + (size_t)r * F + ks * 32 + (lane & 3) * 8;
      g2l(g, lds + (w * 8 + i) * 1024 + lane * 16);
    }
  };

  const unsigned char* Bbase = (const unsigned char*)Bpack + (size_t)w * 6144 + lane * 16;
  const int c = w * 16 + lrow;
  const float br = bih[c] + bhh[c];
  const float bz = bih[128 + c] + bhh[128 + c];
  const float bni = bih[256 + c], bnh = bhh[256 + c];
  const int prow = tid >> 5;        // epilogue phase-2: row within 16-row tile
  const int pcol = (tid & 31) * 4;  // epilogue phase-2: 4 features

  int ch = blockIdx.x;
  stageA(ch * 64);

  for (;;) {
    const int row0 = ch * 64;
    f32x4 acc[16];  // [t*4+q], q: 0=r(merged), 1=z(merged), 2=n_c1, 3=n_c2
#pragma unroll
    for (int i = 0; i < 16; ++i) acc[i] = (f32x4){0.f, 0.f, 0.f, 0.f};
    bf16x8 Bf[2][6];
    bf16x8 Af[2][8];

    asm volatile("s_waitcnt vmcnt(0)" ::: "memory");
    __syncthreads();

    // ---- K-loop: 8 half-steps, 2-deep register pipeline (r8-proven)
    LOADB(0, 0) LOADA(0, 0)
    LOADB(1, 1) LOADA(1, 1) DOMFMA(0, 0)
    LOADB(2, 0) LOADA(2, 0) DOMFMA(1, 1)
    LOADB(3, 1) LOADA(3, 1) DOMFMA(2, 0)
    LOADB(4, 0) LOADA(4, 0) DOMFMA(3, 1)
    LOADB(5, 1) LOADA(5, 1) DOMFMA(4, 0)
    LOADB(6, 0) LOADA(6, 0) DOMFMA(5, 1)
    LOADB(7, 1) LOADA(7, 1) DOMFMA(6, 0)
    DOMFMA(7, 1)

    __syncthreads();  // A region dead; safe to restage for next chunk

    const int nch = ch + gridDim.x;
    const bool more = nch < nchunks;
    if (more) stageA(nch * 64);  // async g2l; latency hides under epilogue

    // ---- early-issue h RMW loads for all 4 sub-phases
    u16x4 evh[4], evl[4];
#pragma unroll
    for (int t = 0; t < 4; ++t) {
      int r = row0 + t * 16 + prow;
      size_t go = (size_t)(r < N ? r : 0) * F + pcol;
      evh[t] = *(const u16x4*)(h_hi_out + go);
      evl[t] = *(const u16x4*)(h_lo_out + go);
    }

    // ---- epilogue: 4 sub-phases of 16 rows (acc tile t), ab in own region
#pragma unroll
    for (int t = 0; t < 4; ++t) {
      {  // phase-1: gates -> (a,b) float2
        unsigned char* abp = lds + ABBASE + (size_t)(kq * 4) * ABSTRIDE + c * 8;
#pragma unroll
        for (int i = 0; i < 4; ++i) {
          const float cr = acc[t * 4 + 0][i];
          const float cz = acc[t * 4 + 1][i];
          const float c1n = acc[t * 4 + 2][i], c2n = acc[t * 4 + 3][i];
          const float rr = 1.f / (1.f + __expf(-(cr + br)));
          const float zz = 1.f / (1.f + __expf(-(cz + bz)));
          const float xx = c1n + bni + rr * (c2n + bnh);
          const float t2 = __expf(2.f * fabsf(xx));           // inf-safe
          const float nn = copysignf(1.f - 2.f / (t2 + 1.f), xx);
          *(float2*)(abp + (size_t)i * ABSTRIDE) = make_float2((1.f - zz) * nn, zz);
        }
      }
      __syncthreads();
      {  // phase-2: wide h RMW for these 16 rows (h_old preloaded)
        const int r = row0 + t * 16 + prow;
        if (r < N) {
          const float2* ab = (const float2*)(lds + ABBASE + (size_t)prow * ABSTRIDE + pcol * 8);
          const size_t go = (size_t)r * F + pcol;
          u16x4 oh, ol;
#pragma unroll
          for (int k2 = 0; k2 < 4; ++k2) {
            float hold = bf16f(evh[t][k2]) + bf16f(evl[t][k2]);
            float2 pq = ab[k2];
            float hn = pq.x + pq.y * hold;
            unsigned short x = bf16_rne(hn);
            oh[k2] = x;
            ol[k2] = bf16_rne(hn - bf16f(x));
          }
          *(u16x4*)(h_hi_out + go) = oh;
          *(u16x4*)(h_lo_out + go) = ol;
        }
      }
      __syncthreads();  // ab consumed before next phase-1 overwrite
    }

    if (!more) break;
    ch = nch;
  }
}

// ---------------------------------------------------------------------------
// final: out[n] = relu(h[n]) . lin_w + lin_b
// ---------------------------------------------------------------------------
__global__ void final_kernel(const unsigned* __restrict__ hh, const unsigned* __restrict__ hl,
                             const float* __restrict__ lin_w,
                             const float* __restrict__ lin_b, float* __restrict__ out, int N) {
  int n = blockIdx.x * 4 + (threadIdx.x >> 6);
  if (n >= N) return;
  int d = threadIdx.x & 63;
  size_t o = (size_t)n * 64 + d;  // u32 view of row-major [node][128] u16
  unsigned wh = hh[o], wl = hl[o];
  float v0 = bf16f((unsigned short)(wh & 0xffff)) + bf16f((unsigned short)(wl & 0xffff));
  float v1 = bf16f((unsigned short)(wh >> 16)) + bf16f((unsigned short)(wl >> 16));
  float sum = fmaxf(v0, 0.f) * lin_w[2 * d] + fmaxf(v1, 0.f) * lin_w[2 * d + 1];
#pragma unroll
  for (int s = 32; s; s >>= 1) sum += __shfl_xor(sum, s, 64);
  if (d == 0) out[n] = sum + lin_b[0];
}

// ---------------------------------------------------------------------------
extern "C" void kernel_launch(void* const* d_in, const int* in_sizes, int n_in,
                              void* d_out, int out_size, void* d_ws, size_t ws_size,
                              hipStream_t stream) {
  const float* x     = (const float*)d_in[0];
  const int*   ei    = (const int*)d_in[1];
  const float* W     = (const float*)d_in[2];
  const float* w_ih  = (const float*)d_in[3];
  const float* w_hh  = (const float*)d_in[4];
  const float* b_ih  = (const float*)d_in[5];
  const float* b_hh  = (const float*)d_in[6];
  const float* lin_w = (const float*)d_in[7];
  const float* lin_b = (const float*)d_in[8];

  const int N = in_sizes[0] / F;
  const int E = in_sizes[1] / 2;
  const int L = in_sizes[2] / (F * F);
  const size_t NF = (size_t)N * F;

  char* p = (char*)d_ws;
  unsigned short* h_hi = (unsigned short*)p; p += NF * 2;
  unsigned short* h_lo = (unsigned short*)p; p += NF * 2;
  unsigned short* s_hi = (unsigned short*)p; p += NF * 2;
  unsigned short* s_lo = (unsigned short*)p; p += NF * 2;
  unsigned short* Bpack = (unsigned short*)p; p += (size_t)L * 196608 * 2;
  int* cnt     = (int*)p; p += (size_t)N * 4;
  int* exscan  = (int*)p; p += (size_t)N * 4;
  int* chunk   = (int*)p; p += 256 * 4;
  int* rowptr  = (int*)p; p += ((size_t)N + 1) * 4;
  int* cursor  = (int*)p; p += (size_t)N * 4;
  int* csr_src = (int*)p; p += (size_t)E * 4;

  const int split_blocks = (N * 16 + 255) / 256;
  const int prep_blocks = (L * 98304 + 255) / 256;
  const int edge_blocks = (E + 255) / 256;
  const int nchunk = (N + 255) / 256;
  const int nchunks = (N + 63) / 64;
  const int gemm_blocks = nchunks < 256 ? nchunks : 256;
  const int node4_blocks = (N + 3) / 4;

  split8_kernel<<<split_blocks, 256, 0, stream>>>(x, h_hi, h_lo, N);
  prep_w_kernel<<<prep_blocks, 256, 0, stream>>>(W, w_ih, w_hh, Bpack, L);

  hipMemsetAsync(cnt, 0, (size_t)N * 4, stream);
  hist_kernel<<<edge_blocks, 256, 0, stream>>>(ei, cnt, E);
  scan1_kernel<<<nchunk, 256, 0, stream>>>(cnt, exscan, chunk, N);
  scan2_kernel<<<1, 256, 0, stream>>>(chunk, nchunk);
  finalize_rowptr_kernel<<<(N + 256) / 256, 256, 0, stream>>>(exscan, chunk, rowptr, cursor, N, E);
  place_kernel<<<edge_blocks, 256, 0, stream>>>(ei, cursor, csr_src, E);

  for (int t = 0; t < L; ++t) {
    gather_kernel<<<node4_blocks, 256, 0, stream>>>(
        h_hi, h_lo, rowptr, csr_src, s_hi, s_lo, N);
    gemm_gru_kernel<<<gemm_blocks, 512, 0, stream>>>(
        s_hi, s_lo, h_hi, h_lo, Bpack + (size_t)t * 196608,
        b_ih, b_hh, h_hi, h_lo, N, nchunks);
  }

  final_kernel<<<node4_blocks, 256, 0, stream>>>(
      (const unsigned*)h_hi, (const unsigned*)h_lo, lin_w, lin_b, (float*)d_out, N);
}

// Round 14
// 620.240 us; speedup vs baseline: 4.5352x; 1.1683x over previous
//
#include <hip/hip_runtime.h>

typedef float f32x4 __attribute__((ext_vector_type(4)));
typedef __bf16 bf16x8 __attribute__((ext_vector_type(8)));
typedef unsigned short u16x8 __attribute__((ext_vector_type(8)));

#define F 128

__device__ __forceinline__ unsigned short bf16_rne(float f) {
  unsigned u = __float_as_uint(f);
  u += 0x7FFFu + ((u >> 16) & 1u);
  return (unsigned short)(u >> 16);
}
__device__ __forceinline__ float bf16f(unsigned short s) {
  return __uint_as_float((unsigned)s << 16);
}

// Activation layout: ROW-MAJOR [node][128] u16 (hi and lo arrays).
// Weight layout FRAG-PACKED: per layer, frag ff = hs*24 + w*3 + part
// (hs = ks*2+g; g=0: Wc, g=1: Whh), storage [ff][hi 1KB][lo 1KB]; frag byte
// l*16+e*2 holds B[part*128 + w*16 + (l&15)][ks*32 + (l>>4)*8 + e].

// ---------------------------------------------------------------------------
// split8: x (f32, row-major) -> row-major bf16 hi/lo
// ---------------------------------------------------------------------------
__global__ void split8_kernel(const float* __restrict__ in,
                              unsigned short* __restrict__ hi, unsigned short* __restrict__ lo,
                              int N) {
  int i = blockIdx.x * 256 + threadIdx.x;  // over N*16
  if (i >= N * 16) return;
  int node = i >> 4, f8 = i & 15;
  const float4* p = (const float4*)(in + (size_t)node * F + f8 * 8);
  float4 a = p[0], b = p[1];
  float v[8] = {a.x, a.y, a.z, a.w, b.x, b.y, b.z, b.w};
  u16x8 vh, vl;
#pragma unroll
  for (int e = 0; e < 8; ++e) {
    unsigned short x = bf16_rne(v[e]);
    vh[e] = x;
    vl[e] = bf16_rne(v[e] - bf16f(x));
  }
  size_t o = (size_t)node * F + f8 * 8;
  *(u16x8*)(hi + o) = vh;
  *(u16x8*)(lo + o) = vl;
}

// ---------------------------------------------------------------------------
// prep_w: frag-packed combined weights.
//   Wc[t][j][k] = dot(W[t][k][:], w_ih[j][:]);  Whh[j][k] = w_hh[j][k]
// ---------------------------------------------------------------------------
__global__ void prep_w_kernel(const float* __restrict__ W, const float* __restrict__ w_ih,
                              const float* __restrict__ w_hh,
                              unsigned short* __restrict__ Bpack, int L) {
  int idx = blockIdx.x * 256 + threadIdx.x;
  if (idx >= L * 98304) return;
  int e = idx & 7;
  int l = (idx >> 3) & 63;
  int fp = idx >> 9;            // frag-value group: L*192
  int part = fp % 3;
  int rest = fp / 3;            // L*64
  int w = rest & 7, g = (rest >> 3) & 1, ks = (rest >> 4) & 3, t = rest >> 6;
  int j = part * 128 + w * 16 + (l & 15);
  int k = ks * 32 + ((l >> 4) & 3) * 8 + e;
  float v;
  if (g == 0) {
    const float* wi = w_ih + (size_t)j * 128;
    const float* wk = W + (size_t)t * 16384 + (size_t)k * 128;
    float acc = 0.f;
#pragma unroll 4
    for (int c = 0; c < 128; ++c) acc = fmaf(wk[c], wi[c], acc);
    v = acc;
  } else {
    v = w_hh[(size_t)j * 128 + k];
  }
  int ff = ((ks * 2 + g) * 8 + w) * 3 + part;
  size_t base = (size_t)t * 196608 + (size_t)ff * 1024 + l * 8 + e;
  unsigned short x = bf16_rne(v);
  Bpack[base] = x;
  Bpack[base + 512] = bf16_rne(v - bf16f(x));
}

// ---------------------------------------------------------------------------
// CSR build
// ---------------------------------------------------------------------------
__global__ void hist_kernel(const int* __restrict__ ei, int* __restrict__ cnt, int E) {
  int e = blockIdx.x * 256 + threadIdx.x;
  if (e < E) atomicAdd(&cnt[ei[E + e]], 1);
}

__global__ void scan1_kernel(const int* __restrict__ cnt, int* __restrict__ exscan,
                             int* __restrict__ chunk_sums, int N) {
  __shared__ int tmp[256];
  int i = blockIdx.x * 256 + threadIdx.x;
  int v = (i < N) ? cnt[i] : 0;
  tmp[threadIdx.x] = v;
  __syncthreads();
#pragma unroll
  for (int off = 1; off < 256; off <<= 1) {
    int a = (threadIdx.x >= off) ? tmp[threadIdx.x - off] : 0;
    __syncthreads();
    tmp[threadIdx.x] += a;
    __syncthreads();
  }
  if (i < N) exscan[i] = tmp[threadIdx.x] - v;
  if (threadIdx.x == 255) chunk_sums[blockIdx.x] = tmp[255];
}

__global__ void scan2_kernel(int* __restrict__ chunk_sums, int nchunk) {
  __shared__ int tmp[256];
  int v = (threadIdx.x < nchunk) ? chunk_sums[threadIdx.x] : 0;
  tmp[threadIdx.x] = v;
  __syncthreads();
#pragma unroll
  for (int off = 1; off < 256; off <<= 1) {
    int a = (threadIdx.x >= off) ? tmp[threadIdx.x - off] : 0;
    __syncthreads();
    tmp[threadIdx.x] += a;
    __syncthreads();
  }
  if (threadIdx.x < nchunk) chunk_sums[threadIdx.x] = tmp[threadIdx.x] - v;
}

__global__ void finalize_rowptr_kernel(const int* __restrict__ exscan,
                                       const int* __restrict__ chunk_sums,
                                       int* __restrict__ rowptr, int* __restrict__ cursor,
                                       int N, int E) {
  int i = blockIdx.x * 256 + threadIdx.x;
  if (i < N) {
    int v = exscan[i] + chunk_sums[i >> 8];
    rowptr[i] = v;
    cursor[i] = v;
  }
  if (i == N) rowptr[N] = E;
}

__global__ void place_kernel(const int* __restrict__ ei, int* __restrict__ cursor,
                             int* __restrict__ csr_src, int E) {
  int e = blockIdx.x * 256 + threadIdx.x;
  if (e >= E) return;
  int pos = atomicAdd(&cursor[ei[E + e]], 1);
  csr_src[pos] = ei[e];
}

// ---------------------------------------------------------------------------
// gather: one wave per node. Lane group grp = lane>>4:
//   grp0: hh edge-parity0, grp1: hl p0, grp2: hh p1, grp3: hl p1.
// 8-edge unroll: 4 u16x8 loads per lane in flight. Combine via shfl_xor.
// ---------------------------------------------------------------------------
__global__ __launch_bounds__(256) void gather_kernel(
    const unsigned short* __restrict__ hh, const unsigned short* __restrict__ hl,
    const int* __restrict__ rowptr, const int* __restrict__ csr_src,
    unsigned short* __restrict__ shi, unsigned short* __restrict__ slo, int N) {
  int node = blockIdx.x * 4 + (threadIdx.x >> 6);
  if (node >= N) return;
  const int lane = threadIdx.x & 63;
  const int grp = lane >> 4, sub = lane & 15;
  const int par = grp >> 1;
  const unsigned short* base = (grp & 1) ? hl : hh;
  const int beg = rowptr[node], end = rowptr[node + 1];
  float a[8] = {0.f, 0.f, 0.f, 0.f, 0.f, 0.f, 0.f, 0.f};
  int j = beg;
  for (; j + 8 <= end; j += 8) {  // 8 edges per iter, 4 loads per lane
    int e0 = csr_src[j + par];
    int e1 = csr_src[j + 2 + par];
    int e2 = csr_src[j + 4 + par];
    int e3 = csr_src[j + 6 + par];
    u16x8 v0 = *(const u16x8*)(base + (size_t)e0 * F + sub * 8);
    u16x8 v1 = *(const u16x8*)(base + (size_t)e1 * F + sub * 8);
    u16x8 v2 = *(const u16x8*)(base + (size_t)e2 * F + sub * 8);
    u16x8 v3 = *(const u16x8*)(base + (size_t)e3 * F + sub * 8);
#pragma unroll
    for (int q = 0; q < 8; ++q)
      a[q] += (bf16f(v0[q]) + bf16f(v1[q])) + (bf16f(v2[q]) + bf16f(v3[q]));
  }
  for (; j + 2 <= end; j += 2) {  // 2 edges
    int e0 = csr_src[j + par];
    u16x8 v0 = *(const u16x8*)(base + (size_t)e0 * F + sub * 8);
#pragma unroll
    for (int q = 0; q < 8; ++q) a[q] += bf16f(v0[q]);
  }
  if (j < end && par == 0) {  // last single edge: only parity-0 groups
    int e0 = csr_src[j];
    u16x8 v0 = *(const u16x8*)(base + (size_t)e0 * F + sub * 8);
#pragma unroll
    for (int q = 0; q < 8; ++q) a[q] += bf16f(v0[q]);
  }
#pragma unroll
  for (int q = 0; q < 8; ++q) {
    a[q] += __shfl_xor(a[q], 32, 64);  // combine edge parities
    a[q] += __shfl_xor(a[q], 16, 64);  // combine hi + lo contributions
  }
  if (grp == 0) {
    u16x8 o;
#pragma unroll
    for (int q = 0; q < 8; ++q) o[q] = bf16_rne(a[q]);
    *(u16x8*)(shi + (size_t)node * F + sub * 8) = o;
  } else if (grp == 1) {
    u16x8 o;
#pragma unroll
    for (int q = 0; q < 8; ++q) {
      unsigned short x = bf16_rne(a[q]);
      o[q] = bf16_rne(a[q] - bf16f(x));
    }
    *(u16x8*)(slo + (size_t)node * F + sub * 8) = o;
  }
}

// ---------------------------------------------------------------------------
// gemm_gru (r8 structure — best verified): one 64-row chunk per block,
// 8 waves; wave w owns feature tile w (16 features) x {r,z,n} for all 64
// rows -> B loaded once per block. A staged once into LDS[0..64K) via
// global_load_lds; K-loop: 8 half-steps, 2-deep register pipeline.
// Epilogue: phase-1 writes (a,b)=((1-z)*n, z) float2 into the SAME LDS
// region (A dead; row stride 1056B breaks bank aliasing); phase-2 remaps
// threads row-major and does the h RMW with wide 16B loads/stores (h_old
// loads issued early, hidden under phase-1). tanh via guarded exp-form.
// ---------------------------------------------------------------------------
__device__ __forceinline__ void g2l(const void* g, void* l) {
  __builtin_amdgcn_global_load_lds((const __attribute__((address_space(1))) void*)g,
                                   (__attribute__((address_space(3))) void*)l, 16, 0, 0);
}

#define LOADB(hs, slot)                                                          \
  {                                                                              \
    const unsigned char* bg = Bbase + (size_t)(hs) * 49152;                      \
    _Pragma("unroll") for (int i = 0; i < 6; ++i)                                \
        Bf[slot][i] = *(const bf16x8*)(bg + i * 1024);                           \
  }
#define LOADA(hs, slot)                                                          \
  {                                                                              \
    const int ks_ = (hs) >> 1, g_ = (hs) & 1;                                    \
    const unsigned char* bh = lds + ((g_ * 2) * 4 + ks_) * 4096 + lrow * 64 + kq * 16;      \
    const unsigned char* bl = lds + ((g_ * 2 + 1) * 4 + ks_) * 4096 + lrow * 64 + kq * 16;  \
    _Pragma("unroll") for (int t = 0; t < 4; ++t) {                              \
      Af[slot][t] = *(const bf16x8*)(bh + t * 1024);                             \
      Af[slot][4 + t] = *(const bf16x8*)(bl + t * 1024);                         \
    }                                                                            \
  }
#define DOMFMA(hs, slot)                                                         \
  {                                                                              \
    const int g_ = (hs) & 1;                                                     \
    __builtin_amdgcn_s_setprio(1);                                               \
    _Pragma("unroll") for (int part = 0; part < 3; ++part)                       \
        _Pragma("unroll") for (int t = 0; t < 4; ++t) {                          \
      const int ai = (t * 3 + part) * 2 + g_;                                    \
      acc[ai] = __builtin_amdgcn_mfma_f32_16x16x32_bf16(Af[slot][t], Bf[slot][part * 2], acc[ai], 0, 0, 0);     \
      acc[ai] = __builtin_amdgcn_mfma_f32_16x16x32_bf16(Af[slot][4 + t], Bf[slot][part * 2], acc[ai], 0, 0, 0); \
      acc[ai] = __builtin_amdgcn_mfma_f32_16x16x32_bf16(Af[slot][t], Bf[slot][part * 2 + 1], acc[ai], 0, 0, 0); \
    }                                                                            \
    __builtin_amdgcn_s_setprio(0);                                               \
  }

#define ABSTRIDE 1056

__global__ __launch_bounds__(512, 2) void gemm_gru_kernel(
    const unsigned short* __restrict__ s_hi, const unsigned short* __restrict__ s_lo,
    const unsigned short* h_hi, const unsigned short* h_lo,
    const unsigned short* __restrict__ Bpack,
    const float* __restrict__ bih, const float* __restrict__ bhh,
    unsigned short* h_hi_out, unsigned short* h_lo_out, int N) {
  __shared__ __align__(1024) unsigned char lds[64 * ABSTRIDE];  // 67584B
  const int tid = threadIdx.x, w = tid >> 6, lane = tid & 63;
  const int lrow = lane & 15, kq = lane >> 4;
  const int row0 = blockIdx.x * 64;

  // ---- stage A: 64 x 1KB chunks into lds[0..64K)
  {
    const int arr = w >> 1;  // wave-constant
    const unsigned short* ap = (arr == 0) ? s_hi : (arr == 1) ? s_lo : (arr == 2) ? h_hi : h_lo;
#pragma unroll
    for (int i = 0; i < 8; ++i) {
      const int ks = (2 * w + (i >> 2)) & 3;
      int r = row0 + (i & 3) * 16 + (lane >> 2);
      if (r >= N) r = N - 1;
      const unsigned short* g = ap + (size_t)r * F + ks * 32 + (lane & 3) * 8;
      g2l(g, lds + (w * 8 + i) * 1024 + lane * 16);
    }
  }

  f32x4 acc[24];  // [(t*3+part)*2 + g]
#pragma unroll
  for (int i = 0; i < 24; ++i) acc[i] = (f32x4){0.f, 0.f, 0.f, 0.f};
  bf16x8 Bf[2][6];
  bf16x8 Af[2][8];

  const unsigned char* Bbase = (const unsigned char*)Bpack + (size_t)w * 6144 + lane * 16;

  asm volatile("s_waitcnt vmcnt(0)" ::: "memory");
  __syncthreads();

  LOADB(0, 0) LOADA(0, 0)
  LOADB(1, 1) LOADA(1, 1) DOMFMA(0, 0)
  LOADB(2, 0) LOADA(2, 0) DOMFMA(1, 1)
  LOADB(3, 1) LOADA(3, 1) DOMFMA(2, 0)
  LOADB(4, 0) LOADA(4, 0) DOMFMA(3, 1)
  LOADB(5, 1) LOADA(5, 1) DOMFMA(4, 0)
  LOADB(6, 0) LOADA(6, 0) DOMFMA(5, 1)
  LOADB(7, 1) LOADA(7, 1) DOMFMA(6, 0)
  DOMFMA(7, 1)

  __syncthreads();  // all waves done reading A-LDS; region becomes ab-space

  // ---- early-issue phase-2's h RMW loads (latency hides under phase-1)
  const int row2 = tid >> 3, seg2 = tid & 7;
  const int r2 = row0 + row2;
  const size_t go2 = (size_t)(r2 < N ? r2 : 0) * F + seg2 * 16;
  u16x8 vh0 = *(const u16x8*)(h_hi_out + go2);
  u16x8 vh1 = *(const u16x8*)(h_hi_out + go2 + 8);
  u16x8 vl0 = *(const u16x8*)(h_lo_out + go2);
  u16x8 vl1 = *(const u16x8*)(h_lo_out + go2 + 8);

  // ---- phase-1: GRU gates -> (a,b) float2 into ab-LDS (stride 1056B/row)
  {
    const int c = w * 16 + lrow;
    const float br = bih[c] + bhh[c];
    const float bz = bih[128 + c] + bhh[128 + c];
    const float bni = bih[256 + c], bnh = bhh[256 + c];
    unsigned char* abp = lds + (size_t)(kq * 4) * ABSTRIDE + c * 8;
#pragma unroll
    for (int t = 0; t < 4; ++t) {
#pragma unroll
      for (int i = 0; i < 4; ++i) {
        const float c1r = acc[(t * 3 + 0) * 2 + 0][i], c2r = acc[(t * 3 + 0) * 2 + 1][i];
        const float c1z = acc[(t * 3 + 1) * 2 + 0][i], c2z = acc[(t * 3 + 1) * 2 + 1][i];
        const float c1n = acc[(t * 3 + 2) * 2 + 0][i], c2n = acc[(t * 3 + 2) * 2 + 1][i];
        const float rr = 1.f / (1.f + __expf(-(c1r + c2r + br)));
        const float zz = 1.f / (1.f + __expf(-(c1z + c2z + bz)));
        const float xx = c1n + bni + rr * (c2n + bnh);
        const float t2 = __expf(2.f * fabsf(xx));            // inf-safe tanh
        const float nn = copysignf(1.f - 2.f / (t2 + 1.f), xx);
        *(float2*)(abp + (size_t)(t * 16 + i) * ABSTRIDE) = make_float2((1.f - zz) * nn, zz);
      }
    }
  }
  __syncthreads();

  // ---- phase-2: row-major wide h RMW: hn = a + b*h_old (h_old preloaded)
  if (r2 < N) {
    const unsigned char* abp = lds + (size_t)row2 * ABSTRIDE + seg2 * 128;
    f32x4 p[8];
#pragma unroll
    for (int k = 0; k < 8; ++k) p[k] = *(const f32x4*)(abp + k * 16);
    u16x8 oh0, oh1, ol0, ol1;
#pragma unroll
    for (int k = 0; k < 4; ++k) {
      float h0 = bf16f(vh0[2 * k]) + bf16f(vl0[2 * k]);
      float h1 = bf16f(vh0[2 * k + 1]) + bf16f(vl0[2 * k + 1]);
      float n0 = p[k].x + p[k].y * h0;
      float n1 = p[k].z + p[k].w * h1;
      unsigned short x0 = bf16_rne(n0), x1 = bf16_rne(n1);
      oh0[2 * k] = x0;
      ol0[2 * k] = bf16_rne(n0 - bf16f(x0));
      oh0[2 * k + 1] = x1;
      ol0[2 * k + 1] = bf16_rne(n1 - bf16f(x1));
    }
#pragma unroll
    for (int k = 0; k < 4; ++k) {
      float h0 = bf16f(vh1[2 * k]) + bf16f(vl1[2 * k]);
      float h1 = bf16f(vh1[2 * k + 1]) + bf16f(vl1[2 * k + 1]);
      float n0 = p[4 + k].x + p[4 + k].y * h0;
      float n1 = p[4 + k].z + p[4 + k].w * h1;
      unsigned short x0 = bf16_rne(n0), x1 = bf16_rne(n1);
      oh1[2 * k] = x0;
      ol1[2 * k] = bf16_rne(n0 - bf16f(x0));
      oh1[2 * k + 1] = x1;
      ol1[2 * k + 1] = bf16_rne(n1 - bf16f(x1));
    }
    *(u16x8*)(h_hi_out + go2) = oh0;
    *(u16x8*)(h_hi_out + go2 + 8) = oh1;
    *(u16x8*)(h_lo_out + go2) = ol0;
    *(u16x8*)(h_lo_out + go2 + 8) = ol1;
  }
}

// ---------------------------------------------------------------------------
// final: out[n] = relu(h[n]) . lin_w + lin_b
// ---------------------------------------------------------------------------
__global__ void final_kernel(const unsigned* __restrict__ hh, const unsigned* __restrict__ hl,
                             const float* __restrict__ lin_w,
                             const float* __restrict__ lin_b, float* __restrict__ out, int N) {
  int n = blockIdx.x * 4 + (threadIdx.x >> 6);
  if (n >= N) return;
  int d = threadIdx.x & 63;
  size_t o = (size_t)n * 64 + d;  // u32 view of row-major [node][128] u16
  unsigned wh = hh[o], wl = hl[o];
  float v0 = bf16f((unsigned short)(wh & 0xffff)) + bf16f((unsigned short)(wl & 0xffff));
  float v1 = bf16f((unsigned short)(wh >> 16)) + bf16f((unsigned short)(wl >> 16));
  float sum = fmaxf(v0, 0.f) * lin_w[2 * d] + fmaxf(v1, 0.f) * lin_w[2 * d + 1];
#pragma unroll
  for (int s = 32; s; s >>= 1) sum += __shfl_xor(sum, s, 64);
  if (d == 0) out[n] = sum + lin_b[0];
}

// ---------------------------------------------------------------------------
extern "C" void kernel_launch(void* const* d_in, const int* in_sizes, int n_in,
                              void* d_out, int out_size, void* d_ws, size_t ws_size,
                              hipStream_t stream) {
  const float* x     = (const float*)d_in[0];
  const int*   ei    = (const int*)d_in[1];
  const float* W     = (const float*)d_in[2];
  const float* w_ih  = (const float*)d_in[3];
  const float* w_hh  = (const float*)d_in[4];
  const float* b_ih  = (const float*)d_in[5];
  const float* b_hh  = (const float*)d_in[6];
  const float* lin_w = (const float*)d_in[7];
  const float* lin_b = (const float*)d_in[8];

  const int N = in_sizes[0] / F;
  const int E = in_sizes[1] / 2;
  const int L = in_sizes[2] / (F * F);
  const size_t NF = (size_t)N * F;

  char* p = (char*)d_ws;
  unsigned short* h_hi = (unsigned short*)p; p += NF * 2;
  unsigned short* h_lo = (unsigned short*)p; p += NF * 2;
  unsigned short* s_hi = (unsigned short*)p; p += NF * 2;
  unsigned short* s_lo = (unsigned short*)p; p += NF * 2;
  unsigned short* Bpack = (unsigned short*)p; p += (size_t)L * 196608 * 2;
  int* cnt     = (int*)p; p += (size_t)N * 4;
  int* exscan  = (int*)p; p += (size_t)N * 4;
  int* chunk   = (int*)p; p += 256 * 4;
  int* rowptr  = (int*)p; p += ((size_t)N + 1) * 4;
  int* cursor  = (int*)p; p += (size_t)N * 4;
  int* csr_src = (int*)p; p += (size_t)E * 4;

  const int split_blocks = (N * 16 + 255) / 256;
  const int prep_blocks = (L * 98304 + 255) / 256;
  const int edge_blocks = (E + 255) / 256;
  const int nchunk = (N + 255) / 256;
  const int gemm_blocks = (N + 63) / 64;
  const int node4_blocks = (N + 3) / 4;

  split8_kernel<<<split_blocks, 256, 0, stream>>>(x, h_hi, h_lo, N);
  prep_w_kernel<<<prep_blocks, 256, 0, stream>>>(W, w_ih, w_hh, Bpack, L);

  hipMemsetAsync(cnt, 0, (size_t)N * 4, stream);
  hist_kernel<<<edge_blocks, 256, 0, stream>>>(ei, cnt, E);
  scan1_kernel<<<nchunk, 256, 0, stream>>>(cnt, exscan, chunk, N);
  scan2_kernel<<<1, 256, 0, stream>>>(chunk, nchunk);
  finalize_rowptr_kernel<<<(N + 256) / 256, 256, 0, stream>>>(exscan, chunk, rowptr, cursor, N, E);
  place_kernel<<<edge_blocks, 256, 0, stream>>>(ei, cursor, csr_src, E);

  for (int t = 0; t < L; ++t) {
    gather_kernel<<<node4_blocks, 256, 0, stream>>>(
        h_hi, h_lo, rowptr, csr_src, s_hi, s_lo, N);
    gemm_gru_kernel<<<gemm_blocks, 512, 0, stream>>>(
        s_hi, s_lo, h_hi, h_lo, Bpack + (size_t)t * 196608,
        b_ih, b_hh, h_hi, h_lo, N);
  }

  final_kernel<<<node4_blocks, 256, 0, stream>>>(
      (const unsigned*)h_hi, (const unsigned*)h_lo, lin_w, lin_b, (float*)d_out, N);
}